// Round 1
// baseline (347.961 us; speedup 1.0000x reference)
//
#include <hip/hip_runtime.h>
#include <math.h>

// Morphological dilation, k=4x4, TF SAME padding (pad top/left=1, bottom/right=2).
// x: (8, 512, 512, 32) fp32 NHWC;  w: (4, 4, 32) fp32;  out: same as x.
// out[b,y,x,c] = max_{i,j} x[b, y+i-1, x+j-1, c] + w[i,j,c]  (OOB -> -inf)

constexpr int H = 512;
constexpr int W = 512;
constexpr int C = 32;
constexpr int T = 8;   // output rows per thread (y-strip)

__device__ __forceinline__ float4 fmax4(float4 a, float4 b) {
    return make_float4(fmaxf(a.x, b.x), fmaxf(a.y, b.y),
                       fmaxf(a.z, b.z), fmaxf(a.w, b.w));
}
__device__ __forceinline__ float4 fadd4(float4 a, float4 b) {
    return make_float4(a.x + b.x, a.y + b.y, a.z + b.z, a.w + b.w);
}

__global__ __launch_bounds__(256)
void dil2d_kernel(const float* __restrict__ xin,
                  const float* __restrict__ wt,
                  float* __restrict__ out) {
    // thread -> (channel-quad, x); block covers 32 x positions * 8 c-quads
    const int c4 = (threadIdx.x & 7) * 4;        // channel offset 0,4,...,28
    const int xl = threadIdx.x >> 3;             // 0..31
    const int xp = blockIdx.x * 32 + xl;         // 0..511
    const int y0 = blockIdx.y * T;               // strip start row
    const int b  = blockIdx.z;

    // hoist the 4x4 weight taps for our 4 channels into registers
    float4 wv[16];
#pragma unroll
    for (int k = 0; k < 16; ++k)
        wv[k] = *reinterpret_cast<const float4*>(wt + k * C + c4);

    const float4 NEG = make_float4(-INFINITY, -INFINITY, -INFINITY, -INFINITY);
    float4 acc[T];
#pragma unroll
    for (int t = 0; t < T; ++t) acc[t] = NEG;

    const float* xb = xin + (size_t)b * H * W * C;

    // slide over the T+3 input rows that feed this strip; each loaded row
    // contributes to up to 4 output rows (one per kernel row i).
#pragma unroll
    for (int r = 0; r < T + 3; ++r) {
        const int yy = y0 - 1 + r;
        if (yy < 0 || yy >= H) continue;   // OOB row == -inf contribution

        float4 px[4];
        const float* rowp = xb + (size_t)yy * W * C + c4;
#pragma unroll
        for (int j = 0; j < 4; ++j) {
            const int xx = xp + j - 1;
            px[j] = (xx >= 0 && xx < W)
                  ? *reinterpret_cast<const float4*>(rowp + (size_t)xx * C)
                  : NEG;
        }

#pragma unroll
        for (int i = 0; i < 4; ++i) {
            const int t = r - i;           // unroll-constant: static acc index
            if (t < 0 || t >= T) continue; // folded at compile time
            float4 v = fadd4(px[0], wv[i * 4 + 0]);
            v = fmax4(v, fadd4(px[1], wv[i * 4 + 1]));
            v = fmax4(v, fadd4(px[2], wv[i * 4 + 2]));
            v = fmax4(v, fadd4(px[3], wv[i * 4 + 3]));
            acc[t] = fmax4(acc[t], v);
        }
    }

    float* ob = out + (((size_t)b * H + y0) * W + xp) * C + c4;
#pragma unroll
    for (int t = 0; t < T; ++t)
        *reinterpret_cast<float4*>(ob + (size_t)t * W * C) = acc[t];
}

extern "C" void kernel_launch(void* const* d_in, const int* in_sizes, int n_in,
                              void* d_out, int out_size, void* d_ws, size_t ws_size,
                              hipStream_t stream) {
    const float* x = (const float*)d_in[0];
    const float* w = (const float*)d_in[1];
    float* o = (float*)d_out;

    dim3 block(256);
    dim3 grid(W * (C / 4) / 256,   // 16: x*cquad tiles
              H / T,               // 64: y strips
              8);                  // batch
    dil2d_kernel<<<grid, block, 0, stream>>>(x, w, o);
}